// Round 5
// baseline (456.663 us; speedup 1.0000x reference)
//
#include <hip/hip_runtime.h>
#include <hip/hip_bf16.h>

typedef __bf16 bf16x8 __attribute__((ext_vector_type(8)));
typedef float  floatx4 __attribute__((ext_vector_type(4)));
typedef float  f32x4   __attribute__((ext_vector_type(4)));

constexpr int B_SZ = 1024, NB = 1024, DIN = 64, DOUT = 64;
constexpr int G    = 4;              // consecutive n per workgroup -> 1 KB contiguous x/out per row
constexpr int MB   = 128;            // batch rows per workgroup
constexpr int CH   = 16;             // rows per staged chunk (one 16-row MFMA m-tile)
constexpr int NCH  = MB / CH;        // 8
constexpr int XSTR = G * DIN + 8;    // 264 bf16 per chunk-row (+8 pad)
constexpr int OSTR = G * DOUT + 4;   // 260 f32  per chunk-row (+4 pad)
constexpr int ROWF = NB * DIN;       // 65536 floats per batch row (same for out)

// raw barrier: order LDS ops across waves WITHOUT draining vmcnt
// (prefetch loads / nontemporal stores stay in flight across it)
__device__ inline void lds_barrier() {
    asm volatile("s_waitcnt lgkmcnt(0)" ::: "memory");
    __builtin_amdgcn_s_barrier();
}

__global__ __launch_bounds__(256, 4)   // cap <=128 VGPR -> 4 blocks/CU (16 waves/CU)
void block_linear_kernel(const float* __restrict__ x,
                         const float* __restrict__ W,
                         const float* __restrict__ bias,
                         float* __restrict__ out)
{
    __shared__ __bf16 xb[CH * XSTR];   // 8448 B, single-buffered (dead after frag reads)
    __shared__ float  ob[CH * OSTR];   // 16640 B  -> 24.6 KB total

    // XCD swizzle: 2048 blocks, xcd = bid&7 under round-robin. Each XCD owns
    // 32 n-groups (2 MiB fp32 of W, L2-resident); the 8 row-tiles of one ng
    // are dispatch-adjacent on the same XCD -> W L2 hits.
    const int bid = blockIdx.x;
    const int xcd = bid & 7;
    const int idx = bid >> 3;                // 0..255
    const int ng  = xcd * 32 + (idx >> 3);   // n-group 0..255
    const int rt  = idx & 7;                 // row-tile 0..7

    const int tid  = threadIdx.x;
    const int w    = tid >> 6;               // wave = local n index (1 n per wave)
    const int lane = tid & 63;
    const int r    = lane & 15;              // A-row / B,D-col
    const int q    = lane >> 4;              // quad

    const size_t colbase = (size_t)ng * (G * DIN);   // float offset of n-slab in a row
    const int    row0    = rt * MB;

    // ---- W[n] -> register B-fragments; each wave owns 1 n (32 VGPRs). ----
    const int n_g = ng * G + w;
    bf16x8 bfrag[4][2];
    float  bv[4];
    {
        const float* wp = W + (size_t)n_g * DOUT * DIN;
        #pragma unroll
        for (int ot = 0; ot < 4; ++ot) {
            bv[ot] = bias[n_g * DOUT + ot * 16 + r];
            #pragma unroll
            for (int ks = 0; ks < 2; ++ks) {
                const float* p = wp + (ot * 16 + r) * DIN + ks * 32 + q * 8;
                const f32x4 f0 = *reinterpret_cast<const f32x4*>(p);
                const f32x4 f1 = *reinterpret_cast<const f32x4*>(p + 4);
                bf16x8 b;
                #pragma unroll
                for (int v = 0; v < 4; ++v) { b[v] = (__bf16)f0[v]; b[4+v] = (__bf16)f1[v]; }
                bfrag[ot][ks] = b;
            }
        }
    }

    // ---- staging: chunk = 16 rows x 1 KB slab. e = i*256+tid -> (row=e>>6, c4=e&63).
    // Each wave instruction covers 64 consecutive e = one full 1 KB row-slab. ----
    auto issue_loads = [&](int c, f32x4 (&raw)[4]) {
        #pragma unroll
        for (int i = 0; i < 4; ++i) {
            const int e = i * 256 + tid;
            const int row = e >> 6, c4 = e & 63;
            const size_t rg = (size_t)(row0 + c * CH + row);
            raw[i] = __builtin_nontemporal_load(
                reinterpret_cast<const f32x4*>(x + rg * ROWF + colbase + c4 * 4));
        }
    };
    auto write_xb = [&](f32x4 (&raw)[4]) {
        #pragma unroll
        for (int i = 0; i < 4; ++i) {
            const int e = i * 256 + tid;
            const int row = e >> 6, c4 = e & 63;
            union { __bf16 h[4]; ushort4 u; } pk;
            #pragma unroll
            for (int v = 0; v < 4; ++v) pk.h[v] = (__bf16)raw[i][v];
            *reinterpret_cast<ushort4*>(&xb[row * XSTR + c4 * 4]) = pk.u;
        }
    };

    f32x4 raw[4], nxt[4];
    issue_loads(0, raw);
    write_xb(raw);
    lds_barrier();                       // xb ready

    for (int c = 0; c < NCH; ++c) {
        if (c + 1 < NCH) issue_loads(c + 1, nxt);   // prefetch under compute

        // A fragments from LDS: A[m=r][k=q*8+j] for this wave's n
        bf16x8 af[2];
        #pragma unroll
        for (int ks = 0; ks < 2; ++ks)
            af[ks] = *reinterpret_cast<const bf16x8*>(
                &xb[r * XSTR + w * 64 + ks * 32 + q * 8]);

        floatx4 acc[4];
        #pragma unroll
        for (int ot = 0; ot < 4; ++ot) acc[ot] = (floatx4){0.f, 0.f, 0.f, 0.f};

        #pragma unroll
        for (int ot = 0; ot < 4; ++ot)
            #pragma unroll
            for (int ks = 0; ks < 2; ++ks)
                acc[ot] = __builtin_amdgcn_mfma_f32_16x16x32_bf16(
                    af[ks], bfrag[ot][ks], acc[ot], 0, 0, 0);

        // D (col=r, row=q*4+reg) + bias -> ob tile
        #pragma unroll
        for (int ot = 0; ot < 4; ++ot)
            #pragma unroll
            for (int reg = 0; reg < 4; ++reg)
                ob[(q * 4 + reg) * OSTR + w * 64 + ot * 16 + r]
                    = acc[ot][reg] + bv[ot];

        lds_barrier();                   // ob complete; xb reads done

        // ob -> global: one full 1 KB row-slab per wave instruction
        #pragma unroll
        for (int i = 0; i < 4; ++i) {
            const int e = i * 256 + tid;
            const int row = e >> 6, c4 = e & 63;
            const size_t rg = (size_t)(row0 + c * CH + row);
            const f32x4 v = *reinterpret_cast<const f32x4*>(&ob[row * OSTR + c4 * 4]);
            __builtin_nontemporal_store(
                v, reinterpret_cast<f32x4*>(out + rg * ROWF + colbase + c4 * 4));
        }

        if (c + 1 < NCH) write_xb(nxt);  // xb dead past frag reads -> overwrite in place

        lds_barrier();                   // ob drained + xb ready for c+1
    }
}

extern "C" void kernel_launch(void* const* d_in, const int* in_sizes, int n_in,
                              void* d_out, int out_size, void* d_ws, size_t ws_size,
                              hipStream_t stream) {
    const float* x  = (const float*)d_in[0];
    const float* W  = (const float*)d_in[1];
    const float* b  = (const float*)d_in[2];
    float* out      = (float*)d_out;

    dim3 grid((NB / G) * (B_SZ / MB));   // 256 * 8 = 2048
    dim3 block(256);
    hipLaunchKernelGGL(block_linear_kernel, grid, block, 0, stream, x, W, b, out);
}